// Round 18
// baseline (521.157 us; speedup 1.0000x reference)
//
#include <hip/hip_runtime.h>

// RouterKT forward. Round 18: attention micro-opts on verified R17 base —
// exp2-domain softmax (log2e folded into QSCALE; exp2f = bare v_exp_f32) and
// s_setprio(1) around attention MFMA clusters (T5). All else identical to R17.

constexpr int DMODEL = 256;
constexpr int SEQ    = 1024;
constexpr int BATCH  = 8;
constexpr int NHEADS = 8;
constexpr int DKDIM  = 32;
constexpr int NDYN_C = 6;
constexpr int NTOK_C = BATCH * SEQ;   // 8192
constexpr int DFF_C  = 1024;

using frag_bf16 = __attribute__((ext_vector_type(8))) short;  // 8 bf16 = 4 VGPR
using f32x4    = __attribute__((ext_vector_type(4))) float;
typedef unsigned short ushort_t;

__device__ __forceinline__ ushort_t f2bf(float f) {
  unsigned u = __float_as_uint(f);
  unsigned r = (u + 0x7fffu + ((u >> 16) & 1u)) >> 16;   // RNE, finite inputs
  return (ushort_t)r;
}

__device__ __forceinline__ unsigned cvt_pk_bf16(float lo, float hi) {
  unsigned r;
  asm("v_cvt_pk_bf16_f32 %0, %1, %2" : "=v"(r) : "v"(lo), "v"(hi));
  return r;
}

#define GLOAD_LDS16(gsrc, ldst)                                             \
  __builtin_amdgcn_global_load_lds(                                         \
      (const __attribute__((address_space(1))) void*)(gsrc),                \
      (__attribute__((address_space(3))) void*)(ldst), 16, 0, 0)

// Explicit drain + order pin + barrier (race-proof prefetch handoff).
#define SYNC_DRAIN()                                                        \
  do {                                                                      \
    asm volatile("s_waitcnt vmcnt(0) lgkmcnt(0)" ::: "memory");             \
    __builtin_amdgcn_sched_barrier(0);                                      \
    __syncthreads();                                                        \
  } while (0)

// Counted-vmcnt barrier (T4): wait until all but the newest N of THIS wave's
// vmem ops retired, then raw s_barrier (no implicit vmcnt(0) drain).
#define CBAR_VM(N)                                                          \
  do {                                                                      \
    asm volatile("s_waitcnt vmcnt(" #N ")" ::: "memory");                   \
    __builtin_amdgcn_sched_barrier(0);                                      \
    __builtin_amdgcn_s_barrier();                                           \
    __builtin_amdgcn_sched_barrier(0);                                      \
  } while (0)

// ---------------- bf16 MFMA GEMM body (2-phase prefetch, explicit drain) ------
// C[m][n] = sum_k A[m][k] * B[n][k] + bias.   A:[M][K] bf16, B:[N][K] bf16.
// Tile: BM=64, BN=64, BK=64, double-buffered. 256 threads = 4 waves (2x2).
// mode: 0 = f32 C, 1 = bf16*QSCALE (q-proj), 2 = bf16+relu, 3 = vbT scatter.
__device__ __forceinline__
void gemm_body(int mode, int bx, int by,
               const ushort_t* __restrict__ A, const ushort_t* __restrict__ B,
               const float* __restrict__ bias, void* __restrict__ Cp,
               int M, int N, int K,
               ushort_t (*sA)[4096], ushort_t (*sB)[4096]) {
  const int tid = threadIdx.x;
  const int wid = tid >> 6, lane = tid & 63;
  const int li = lane & 15, g = lane >> 4;
  const int wr = wid >> 1, wc = wid & 1;
  const int m0 = by * 64, n0 = bx * 64;
  f32x4 acc[2][2] = {};
  const int srow = wid * 8 + (lane >> 3);
  const int schk = (lane & 7) ^ (lane >> 3);
  const ushort_t* gA1 = &A[(size_t)(m0 + srow) * K + schk * 8];
  const ushort_t* gA2 = &A[(size_t)(m0 + 32 + srow) * K + schk * 8];
  const ushort_t* gB1 = &B[(size_t)(n0 + srow) * K + schk * 8];
  const ushort_t* gB2 = &B[(size_t)(n0 + 32 + srow) * K + schk * 8];
  const int nk = K >> 6;

  GLOAD_LDS16(gA1, sA[0] + wid * 512);
  GLOAD_LDS16(gA2, sA[0] + 2048 + wid * 512);
  GLOAD_LDS16(gB1, sB[0] + wid * 512);
  GLOAD_LDS16(gB2, sB[0] + 2048 + wid * 512);
  SYNC_DRAIN();

  auto compute = [&](int cur) {
#pragma unroll
    for (int s = 0; s < 2; ++s) {
      frag_bf16 af[2], bf[2];
#pragma unroll
      for (int m = 0; m < 2; ++m) {
        const int row = wr * 32 + m * 16 + li;
        af[m] = *reinterpret_cast<const frag_bf16*>(
            &sA[cur][row * 64 + ((s * 4 + g) ^ (row & 7)) * 8]);
      }
#pragma unroll
      for (int n = 0; n < 2; ++n) {
        const int row = wc * 32 + n * 16 + li;
        bf[n] = *reinterpret_cast<const frag_bf16*>(
            &sB[cur][row * 64 + ((s * 4 + g) ^ (row & 7)) * 8]);
      }
#pragma unroll
      for (int m = 0; m < 2; ++m)
#pragma unroll
        for (int n = 0; n < 2; ++n)
          acc[m][n] = __builtin_amdgcn_mfma_f32_16x16x32_bf16(af[m], bf[n], acc[m][n], 0, 0, 0);
    }
  };

  for (int kt = 0; kt < nk - 1; ++kt) {
    const int cur = kt & 1;
    const int k1 = (kt + 1) << 6;
    GLOAD_LDS16(gA1 + k1, sA[cur ^ 1] + wid * 512);
    GLOAD_LDS16(gA2 + k1, sA[cur ^ 1] + 2048 + wid * 512);
    GLOAD_LDS16(gB1 + k1, sB[cur ^ 1] + wid * 512);
    GLOAD_LDS16(gB2 + k1, sB[cur ^ 1] + 2048 + wid * 512);
    compute(cur);
    SYNC_DRAIN();
  }
  compute((nk - 1) & 1);

  // QSCALE^2 = log2(e)/sqrt(32): S arrives in exp2 domain (e^S == exp2(S')).
  constexpr float QSCALE = 0.5050284523f;
#pragma unroll
  for (int m = 0; m < 2; ++m)
#pragma unroll
    for (int n = 0; n < 2; ++n)
#pragma unroll
      for (int r = 0; r < 4; ++r) {
        const int mg = m0 + wr * 32 + m * 16 + g * 4 + r;
        const int ng = n0 + wc * 32 + n * 16 + li;
        if (mode == 0) {
          ((float*)Cp)[(size_t)mg * N + ng] = acc[m][n][r] + bias[ng];
        } else if (mode == 1) {
          ((ushort_t*)Cp)[(size_t)mg * N + ng] = f2bf((acc[m][n][r] + bias[ng]) * QSCALE);
        } else if (mode == 2) {
          ((ushort_t*)Cp)[(size_t)mg * N + ng] = f2bf(fmaxf(acc[m][n][r] + bias[ng], 0.0f));
        } else {
          ((ushort_t*)Cp)[((size_t)((ng >> 10) * 256 + mg)) * SEQ + (ng & 1023)] =
              f2bf(acc[m][n][r] + bias[mg]);
        }
      }
}

__global__ __launch_bounds__(256)
void gemm_mfma_k(int mode, const ushort_t* __restrict__ A, const ushort_t* __restrict__ B,
                 const float* __restrict__ bias, void* __restrict__ Cp,
                 int M, int N, int K) {
  __shared__ ushort_t sA[2][4096];
  __shared__ ushort_t sB[2][4096];
  gemm_body(mode, blockIdx.x, blockIdx.y, A, B, bias, Cp, M, N, K, sA, sB);
}

// ---------------- fused GEMM (N=256 full width) + bias + residual + LayerNorm --
// BM=16, BN=256, BK=64, 2-phase prefetch. Grid 512 (2 blocks/CU).
__global__ __launch_bounds__(256)
void gemm_ln_k(const ushort_t* __restrict__ A, const ushort_t* __restrict__ B,
               const float* __restrict__ bias,
               const float* __restrict__ Xin, float* __restrict__ Xout,
               ushort_t* __restrict__ Xbf,
               const float* __restrict__ gam, const float* __restrict__ bet,
               int K) {
  __shared__ ushort_t sA[2][1024];     // 16 x 64
  __shared__ ushort_t sB[2][16384];    // 256 x 64
  __shared__ float ws1[4][16];
  __shared__ float ws2[4][16];
  const int tid = threadIdx.x;
  const int wid = tid >> 6, lane = tid & 63;
  const int li = lane & 15, g = lane >> 4;
  const int wc = wid;                  // 0..3: 64-col slab
  const int m0 = blockIdx.x * 16;
  f32x4 acc[4] = {};
  const int arow = (wid & 1) * 8 + (lane >> 3);
  const int achk = (lane & 7) ^ (lane >> 3);          // arow&7 == lane>>3
  const ushort_t* gA = &A[(size_t)(m0 + arow) * K + achk * 8];
  const int srow = tid >> 3;           // 0..31
  const int schk = (tid & 7) ^ (srow & 7);
  const ushort_t* gB = &B[(size_t)srow * K + schk * 8];
  const int nk = K >> 6;

  auto stage = [&](int k0, int buf) {
    if (wid < 2) GLOAD_LDS16(gA + k0, sA[buf] + wid * 512);
#pragma unroll
    for (int i = 0; i < 8; ++i)
      GLOAD_LDS16(gB + (size_t)i * 32 * K + k0, sB[buf] + i * 2048 + wid * 512);
  };

  stage(0, 0);
  SYNC_DRAIN();

  auto compute = [&](int cur) {
#pragma unroll
    for (int s = 0; s < 2; ++s) {
      frag_bf16 af, bf[4];
      af = *reinterpret_cast<const frag_bf16*>(
          &sA[cur][li * 64 + ((s * 4 + g) ^ (li & 7)) * 8]);
#pragma unroll
      for (int n = 0; n < 4; ++n) {
        const int row = wc * 64 + n * 16 + li;
        bf[n] = *reinterpret_cast<const frag_bf16*>(
            &sB[cur][row * 64 + ((s * 4 + g) ^ (row & 7)) * 8]);
      }
#pragma unroll
      for (int n = 0; n < 4; ++n)
        acc[n] = __builtin_amdgcn_mfma_f32_16x16x32_bf16(af, bf[n], acc[n], 0, 0, 0);
    }
  };

  for (int kt = 0; kt < nk - 1; ++kt) {
    const int cur = kt & 1;
    stage((kt + 1) << 6, cur ^ 1);
    compute(cur);
    SYNC_DRAIN();
  }
  compute((nk - 1) & 1);

  // ---- epilogue: bias + residual, row stats (16 rows), LN, dual store ----
  float xv[4][4];
  float s1[4] = {}, s2[4] = {};
#pragma unroll
  for (int n = 0; n < 4; ++n)
#pragma unroll
    for (int r = 0; r < 4; ++r) {
      const int row = g * 4 + r;
      const int ng = wc * 64 + n * 16 + li;
      const float x = acc[n][r] + bias[ng] + Xin[(size_t)(m0 + row) * DMODEL + ng];
      xv[n][r] = x;
      s1[r] += x;
      s2[r] += x * x;
    }
#pragma unroll
  for (int mask = 1; mask <= 8; mask <<= 1)
#pragma unroll
    for (int r = 0; r < 4; ++r) {
      s1[r] += __shfl_xor(s1[r], mask, 64);
      s2[r] += __shfl_xor(s2[r], mask, 64);
    }
  if (li == 0) {
#pragma unroll
    for (int r = 0; r < 4; ++r) {
      ws1[wid][g * 4 + r] = s1[r];
      ws2[wid][g * 4 + r] = s2[r];
    }
  }
  __syncthreads();
#pragma unroll
  for (int r = 0; r < 4; ++r) {
    const int row = g * 4 + r;
    const float S1 = ws1[0][row] + ws1[1][row] + ws1[2][row] + ws1[3][row];
    const float S2 = ws2[0][row] + ws2[1][row] + ws2[2][row] + ws2[3][row];
    const float mean = S1 * (1.0f / DMODEL);
    const float var = fmaxf(S2 * (1.0f / DMODEL) - mean * mean, 0.0f);
    const float rstd = 1.0f / sqrtf(var + 1e-5f);
#pragma unroll
    for (int n = 0; n < 4; ++n) {
      const int ng = wc * 64 + n * 16 + li;
      const float rv = (xv[n][r] - mean) * rstd * gam[ng] + bet[ng];
      Xout[(size_t)(m0 + row) * DMODEL + ng] = rv;
      Xbf[(size_t)(m0 + row) * DMODEL + ng] = f2bf(rv);
    }
  }
}

// ---------------- Router body (verified, 128 rows/block, 256-thread guards) ----
__device__ __forceinline__
void router_body(const float* __restrict__ R, const float* __restrict__ Wg,
                 float* __restrict__ partials, float* sW, float (*red)[128]) {
  const int tid = threadIdx.x;
  for (int t = tid; t < DMODEL * NDYN_C; t += 256) sW[t] = Wg[t];
  __syncthreads();
  if (tid < 128) {
    const int r = blockIdx.x * 128 + tid;
    const int b = r >> 10;
    const int h = (r >> 7) & 7;
    const int s8 = r & 127;
    float lg[NDYN_C] = {};
    for (int t8 = 0; t8 < 8; ++t8) {
      const float* base = &R[((size_t)(b * SEQ + s8 * 8 + t8)) * DMODEL + h * DKDIM];
#pragma unroll
      for (int d = 0; d < DKDIM; ++d) {
        const float x = base[d];
        const float* w = &sW[(t8 * 32 + d) * NDYN_C];
#pragma unroll
        for (int j = 0; j < NDYN_C; ++j) lg[j] = fmaf(x, w[j], lg[j]);
      }
    }
    float mx = lg[0];
#pragma unroll
    for (int j = 1; j < NDYN_C; ++j) mx = fmaxf(mx, lg[j]);
    float e[NDYN_C], sum = 0.0f;
#pragma unroll
    for (int j = 0; j < NDYN_C; ++j) { e[j] = expf(lg[j] - mx); sum += e[j]; }
    float g[NDYN_C];
#pragma unroll
    for (int j = 0; j < NDYN_C; ++j) g[j] = e[j] / sum;
    int j1 = 0;
#pragma unroll
    for (int j = 1; j < NDYN_C; ++j) if (g[j] > g[j1]) j1 = j;
    int j2 = -1;
#pragma unroll
    for (int j = 0; j < NDYN_C; ++j) {
      if (j == j1) continue;
      if (j2 < 0 || g[j] > g[j2]) j2 = j;
    }
#pragma unroll
    for (int j = 0; j < NDYN_C; ++j) {
      const bool sel = (j == j1) || (j == j2);
      red[j][tid] = sel ? g[j] : 0.0f;
      red[6 + j][tid] = sel ? 1.0f : 0.0f;
      red[12 + j][tid] = g[j];
    }
  }
  __syncthreads();
  if (tid < 18) {
    float s = 0.0f;
    for (int i = 0; i < 128; ++i) s += red[tid][i];
    partials[blockIdx.x * 18 + tid] = s;
  }
}

// merged Q-projection (mode 1) + V-projection (mode 3) + router slice.
__global__ __launch_bounds__(256)
void gemm_qv_router_k(const ushort_t* __restrict__ Aq, const ushort_t* __restrict__ Bq,
                      const float* __restrict__ biasq, void* __restrict__ Cq,
                      const ushort_t* __restrict__ Av, const ushort_t* __restrict__ Bv,
                      const float* __restrict__ biasv, void* __restrict__ Cv,
                      const float* __restrict__ R, const float* __restrict__ Wg,
                      float* __restrict__ partials) {
  __shared__ ushort_t sA[2][4096];   // 16 KB
  __shared__ ushort_t sB[2][4096];   // 16 KB
  if (blockIdx.y == 4) {
    if (blockIdx.z == 0 && blockIdx.x < 64) {
      float* sW = (float*)&sA[0][0];                   // 6 KB <= 16 KB
      float (*red)[128] = (float(*)[128])&sB[0][0];    // 9 KB <= 16 KB
      router_body(R, Wg, partials, sW, red);
    }
    return;
  }
  if (blockIdx.z == 0)
    gemm_body(1, blockIdx.y, blockIdx.x, Aq, Bq, biasq, Cq, NTOK_C, DMODEL, DMODEL, sA, sB);
  else
    gemm_body(3, blockIdx.x, blockIdx.y, Av, Bv, biasv, Cv, DMODEL, NTOK_C, DMODEL, sA, sB);
}

// ---------------- weight transpose body ----------------
__device__ __forceinline__
void transpose_body(const float* __restrict__ ip, ushort_t* __restrict__ op, int R, int C,
                    int c0, int r0) {
  __shared__ float t[32][33];
  const int tx = threadIdx.x & 31, ty = threadIdx.x >> 5;   // ty 0..7
#pragma unroll
  for (int i = 0; i < 4; ++i) t[ty + 8 * i][tx] = ip[(size_t)(r0 + ty + 8 * i) * C + c0 + tx];
  __syncthreads();
#pragma unroll
  for (int i = 0; i < 4; ++i)
    op[(size_t)(c0 + ty + 8 * i) * R + r0 + tx] = f2bf(t[tx][ty + 8 * i]);
}

// ---------------- ALL weight prep + activation init in ONE launch --------------
// grid 8320: [0,1152) Wq/Wv/Wo transposes; [1152,2688) Wf1; [2688,4224) Wf2;
// [4224,8320) f32 copy + bf16 mirror of both activation streams.
__global__ __launch_bounds__(256)
void prep_k(const float* __restrict__ Wq, ushort_t* __restrict__ WqT,
            const float* __restrict__ Wv, ushort_t* __restrict__ WvT,
            const float* __restrict__ Wo, ushort_t* __restrict__ WoT,
            const float* __restrict__ Wf1, ushort_t* __restrict__ Wf1T,
            const float* __restrict__ Wf2, ushort_t* __restrict__ Wf2T,
            const float* __restrict__ q_embed, float* __restrict__ xbuf,
            ushort_t* __restrict__ xbf,
            const float* __restrict__ qa_embed, float* __restrict__ ybuf,
            ushort_t* __restrict__ ybf) {
  const int id = blockIdx.x;
  if (id < 1152) {                     // 18 z-slices of 8x8 blocks (256x256 stacks)
    const int z = id >> 6, rem = id & 63;
    const int zi = z / 6, zz = z % 6;
    const float* in = (zi == 0) ? Wq : (zi == 1) ? Wv : Wo;
    ushort_t* outp = (zi == 0) ? WqT : (zi == 1) ? WvT : WoT;
    transpose_body(in + (size_t)zz * DMODEL * DMODEL, outp + (size_t)zz * DMODEL * DMODEL,
                   DMODEL, DMODEL, (rem & 7) * 32, (rem >> 3) * 32);
  } else if (id < 2688) {              // Wf1 [6][256][1024] -> [6][1024][256]
    const int t = id - 1152;
    const int z = t >> 8, rem = t & 255;
    transpose_body(Wf1 + (size_t)z * DMODEL * DFF_C, Wf1T + (size_t)z * DMODEL * DFF_C,
                   DMODEL, DFF_C, (rem & 31) * 32, (rem >> 5) * 32);
  } else if (id < 4224) {              // Wf2 [6][1024][256] -> [6][256][1024]
    const int t = id - 2688;
    const int z = t >> 8, rem = t & 255;
    transpose_body(Wf2 + (size_t)z * DFF_C * DMODEL, Wf2T + (size_t)z * DFF_C * DMODEL,
                   DFF_C, DMODEL, (rem & 7) * 32, (rem >> 3) * 32);
  } else {                             // activation copy+mirror (4096 blocks)
    const int t = id - 4224;
    const int yy = t >> 11, xx = t & 2047;
    const float* src = yy ? qa_embed : q_embed;
    float* dstF = yy ? ybuf : xbuf;
    ushort_t* dstB = yy ? ybf : xbf;
    const int i = xx * 256 + threadIdx.x;       // over float4 elements
    const float4 v = reinterpret_cast<const float4*>(src)[i];
    reinterpret_cast<float4*>(dstF)[i] = v;
    ushort4 bb;
    bb.x = f2bf(v.x); bb.y = f2bf(v.y); bb.z = f2bf(v.z); bb.w = f2bf(v.w);
    reinterpret_cast<ushort4*>(dstB)[i] = bb;
  }
}

// ---------------- MFMA flash attention: balanced q-block pairs (R15 verified) --
// grid 512: b = gid&7 (XCD-local K/V); slot=gid>>3: h=slot>>3, pair=slot&7.
// Each block runs TWO q-blocks {15-pair, pair}: uniform 17 tile-steps per block.
// S is in exp2 domain (QSCALE carries log2e); p = exp2f(S - m) == e^(orig).
__global__ __launch_bounds__(256)
void attn_mfma_k(const ushort_t* __restrict__ qb, const ushort_t* __restrict__ vbT,
                 const float* __restrict__ partials, ushort_t* __restrict__ out,
                 int mask_val) {
  __shared__ ushort_t sk[3][2048];   // K tile: [kb 4][g 4][li=key 16][8] frag-linear
  __shared__ ushort_t sv[3][2048];   // V^T tile: [d 32][8 chunks, slot = ch^(d&7)][8]
  __shared__ ushort_t pbuf[4096];    // per-wave P^T frag-linear
  const int gid = blockIdx.x;
  const int b = gid & 7;
  const int slot = gid >> 3;
  const int h = (slot >> 3) & 7;
  const int pair = slot & 7;
  const int tid = threadIdx.x;
  const int wave = tid >> 6, lane = tid & 63;
  const int g = lane >> 4, li = lane & 15;
  ushort_t* pP = &pbuf[wave * 1024];

  const ushort_t* gK = &qb[((size_t)(b * SEQ + wave * 16 + li)) * DMODEL + h * DKDIM + g * 8];
  const ushort_t* gV = &vbT[((size_t)((b * NHEADS + h) * DKDIM) + wave * 8 + (lane >> 3)) * SEQ
                            + ((lane & 7) ^ (lane >> 3)) * 8];

  // rt from partials: 1 for shared heads, mean gate otherwise (same order as reduce).
  float rt = 1.0f;
  if (h >= 2) {
    const int j = h - 2;
    float sr = 0.f;
#pragma unroll
    for (int t = 0; t < 8; ++t) sr += partials[(b * 8 + t) * 18 + j];
    rt = sr * (1.0f / 1024.0f);
  }

  auto issue = [&](int i, int bi) {
    GLOAD_LDS16(gK + (size_t)(i * 64) * DMODEL, sk[bi] + wave * 512);
    GLOAD_LDS16(gV + i * 64, sv[bi] + wave * 512);
  };

  auto process = [&](int qblk) {
    const int q0 = qblk * 64;
    const int qw = q0 + wave * 16;
    const int qrow = qw + li;          // this lane's q row
    const frag_bf16 qf = *reinterpret_cast<const frag_bf16*>(
        &qb[((size_t)(b * SEQ + qrow)) * DMODEL + h * DKDIM + g * 8]);
    float mrun = -INFINITY, lrun = 0.f;
    f32x4 o0 = {0.f, 0.f, 0.f, 0.f}, o1 = {0.f, 0.f, 0.f, 0.f};  // O^T
    const int nt = qblk + 1;

    auto tile_step = [&](int t, int cur) {
      const int kt = t * 64;
      f32x4 s[4];
      __builtin_amdgcn_s_setprio(1);
#pragma unroll
      for (int kb = 0; kb < 4; ++kb) {
        frag_bf16 kf = *reinterpret_cast<const frag_bf16*>(&sk[cur][(kb * 64 + g * 16 + li) * 8]);
        f32x4 z = {0.f, 0.f, 0.f, 0.f};
        s[kb] = __builtin_amdgcn_mfma_f32_16x16x32_bf16(kf, qf, z, 0, 0, 0);
      }
      __builtin_amdgcn_s_setprio(0);
      const bool need_mask = (kt + 63) >= (qw + mask_val);
      if (need_mask) {
#pragma unroll
        for (int kb = 0; kb < 4; ++kb)
#pragma unroll
          for (int r = 0; r < 4; ++r) {
            const int col = kt + kb * 16 + 4 * g + r;
            if (col >= (qrow + mask_val)) s[kb][r] = -1e9f;
          }
      }
      float tm = -INFINITY;
#pragma unroll
      for (int kb = 0; kb < 4; ++kb)
#pragma unroll
        for (int r = 0; r < 4; ++r) tm = fmaxf(tm, s[kb][r]);
      tm = fmaxf(tm, __shfl_xor(tm, 16, 64));
      tm = fmaxf(tm, __shfl_xor(tm, 32, 64));
      const float mnew = fmaxf(mrun, tm);
      const float scl = exp2f(mrun - mnew);   // S in exp2 domain
      float p[4][4];
      float psum = 0.f;
#pragma unroll
      for (int kb = 0; kb < 4; ++kb)
#pragma unroll
        for (int r = 0; r < 4; ++r) { p[kb][r] = exp2f(s[kb][r] - mnew); psum += p[kb][r]; }
      psum += __shfl_xor(psum, 16, 64);
      psum += __shfl_xor(psum, 32, 64);
      lrun = lrun * scl + psum;
      mrun = mnew;
#pragma unroll
      for (int r = 0; r < 4; ++r) { o0[r] *= scl; o1[r] *= scl; }
#pragma unroll
      for (int kb = 0; kb < 4; ++kb)
#pragma unroll
        for (int pr = 0; pr < 2; ++pr) {
          const unsigned pk = cvt_pk_bf16(p[kb][2 * pr], p[kb][2 * pr + 1]);
          const int addr = (((kb >> 1) * 4 + (kb & 1) * 2 + (g >> 1)) * 16 + li) * 8
                           + 4 * (g & 1) + 2 * pr;
          *reinterpret_cast<unsigned*>(&pP[addr]) = pk;
        }
      __threadfence_block();
      __builtin_amdgcn_s_setprio(1);
#pragma unroll
      for (int c = 0; c < 2; ++c) {
        frag_bf16 pf = *reinterpret_cast<const frag_bf16*>(&pP[((c * 4 + g) * 16 + li) * 8]);
        frag_bf16 vf0 = *reinterpret_cast<const frag_bf16*>(
            &sv[cur][li * 64 + ((4 * c + g) ^ (li & 7)) * 8]);
        frag_bf16 vf1 = *reinterpret_cast<const frag_bf16*>(
            &sv[cur][(16 + li) * 64 + ((4 * c + g) ^ (li & 7)) * 8]);
        o0 = __builtin_amdgcn_mfma_f32_16x16x32_bf16(vf0, pf, o0, 0, 0, 0);
        o1 = __builtin_amdgcn_mfma_f32_16x16x32_bf16(vf1, pf, o1, 0, 0, 0);
      }
      __builtin_amdgcn_s_setprio(0);
    };

    // prologue: stage tiles 0 (and 1); wait for tile 0 only.
    issue(0, 0);
    if (nt > 1) {
      issue(1, 1);
      CBAR_VM(2);
    } else {
      CBAR_VM(0);
    }

    int cur = 0;
    for (int t = 0; t < nt; ++t) {
      const bool have2 = (t + 2 < nt);
      if (have2) issue(t + 2, (cur + 2 >= 3) ? cur - 1 : cur + 2);
      tile_step(t, cur);
      if (t + 1 < nt) {
        if (have2) { CBAR_VM(2); } else { CBAR_VM(0); }
      }
      cur = (cur + 1 == 3) ? 0 : cur + 1;
    }

    const float mult = rt / lrun;
    if (!(mask_val == 0 && qrow == 0)) {
      const size_t base = (size_t)(b * SEQ + qrow) * DMODEL + h * DKDIM;
      ushort4 w0, w1;
      w0.x = f2bf(o0[0] * mult); w0.y = f2bf(o0[1] * mult);
      w0.z = f2bf(o0[2] * mult); w0.w = f2bf(o0[3] * mult);
      w1.x = f2bf(o1[0] * mult); w1.y = f2bf(o1[1] * mult);
      w1.z = f2bf(o1[2] * mult); w1.w = f2bf(o1[3] * mult);
      *reinterpret_cast<ushort4*>(&out[base + 4 * g]) = w0;
      *reinterpret_cast<ushort4*>(&out[base + 16 + 4 * g]) = w1;
    }
    // fused row0 patch: out[b,0,h,:] = mean_k(V[k,:]) * rt
    if (mask_val == 0 && qblk == 0 && wave == 0) {
      const int d = lane >> 1, hf = lane & 1;
      const ushort_t* src = &vbT[(((size_t)(b * NHEADS + h)) * DKDIM + d) * SEQ + hf * 512];
      float s = 0.f;
      for (int k = 0; k < 512; k += 8) {
        frag_bf16 v = *reinterpret_cast<const frag_bf16*>(&src[k]);
#pragma unroll
        for (int j = 0; j < 8; ++j)
          s += __uint_as_float(((unsigned)(ushort_t)v[j]) << 16);
      }
      s += __shfl_xor(s, 1, 64);
      if (hf == 0)
        out[(size_t)(b * SEQ) * DMODEL + h * DKDIM + d] = f2bf(s * (1.0f / 1024.0f) * rt);
    }
  };

  process(15 - pair);   // heavy phase: nt = 16-pair (9..16)
  SYNC_DRAIN();         // phase handoff: no in-flight loads / pending LDS reads
  process(pair);        // light phase: nt = pair+1 (1..8); total = 17 per block
}

// ---------------- router finalize: launched ONLY for the last layer (bal) -----
__global__ void router_reduce_k(const float* __restrict__ partials,
                                float* __restrict__ bal_out) {
  if (threadIdx.x == 0) {
    float hs[6], hp[6];
    float hssum = 0.0f, hpsum = 0.0f;
    for (int j = 0; j < 6; ++j) {
      float a = 0.0f, c = 0.0f;
      for (int bi = 0; bi < 64; ++bi) {
        a += partials[bi * 18 + 6 + j];
        c += partials[bi * 18 + 12 + j];
      }
      hs[j] = a;
      hp[j] = c * (1.0f / 8192.0f);
      hssum += hs[j];
      hpsum += hp[j];
    }
    float bal = 0.0f;
    for (int j = 0; j < 6; ++j)
      bal += (hs[j] / (hssum + 1e-5f)) * (hp[j] / (hpsum + 1e-5f));
    *bal_out = bal;
  }
}

// ---------------- driver ----------------
extern "C" void kernel_launch(void* const* d_in, const int* in_sizes, int n_in,
                              void* d_out, int out_size, void* d_ws, size_t ws_size,
                              hipStream_t stream) {
  const float* q_embed  = (const float*)d_in[0];
  const float* qa_embed = (const float*)d_in[1];
  const float* Wq  = (const float*)d_in[2];
  const float* bq  = (const float*)d_in[3];
  const float* Wv  = (const float*)d_in[4];
  const float* bv  = (const float*)d_in[5];
  const float* Wg  = (const float*)d_in[6];
  const float* Wo  = (const float*)d_in[7];
  const float* bo  = (const float*)d_in[8];
  const float* ln1w = (const float*)d_in[9];
  const float* ln1b = (const float*)d_in[10];
  const float* Wf1 = (const float*)d_in[11];
  const float* bf1 = (const float*)d_in[12];
  const float* Wf2 = (const float*)d_in[13];
  const float* bf2 = (const float*)d_in[14];
  const float* ln2w = (const float*)d_in[15];
  const float* ln2b = (const float*)d_in[16];
  float* out = (float*)d_out;

  const size_t NA = (size_t)NTOK_C * DMODEL;  // 2097152
  float* xbuf = (float*)d_ws;
  float* ybuf = xbuf + NA;
  float* ob   = ybuf + NA;
  float* routing8   = ob + NA;
  float* partials   = routing8 + 64;
  float* balscratch = partials + 64 * 18;
  ushort_t* xbf   = (ushort_t*)(balscratch + 16);
  ushort_t* ybf   = xbf + NA;
  ushort_t* qb_bf = ybf + NA;
  ushort_t* vbT   = qb_bf + NA;
  ushort_t* ab_bf = vbT + NA;
  ushort_t* hb    = ab_bf + NA;                       // NTOK * DFF bf16
  ushort_t* WqT   = hb + (size_t)NTOK_C * DFF_C;
  ushort_t* WvT   = WqT + (size_t)6 * DMODEL * DMODEL;
  ushort_t* WoT   = WvT + (size_t)6 * DMODEL * DMODEL;
  ushort_t* Wf1T  = WoT + (size_t)6 * DMODEL * DMODEL;
  ushort_t* Wf2T  = Wf1T + (size_t)6 * DMODEL * DFF_C;

  // all weight prep + activation init in one launch
  prep_k<<<8320, 256, 0, stream>>>(Wq, WqT, Wv, WvT, Wo, WoT, Wf1, Wf1T, Wf2, Wf2T,
                                   q_embed, xbuf, xbf, qa_embed, ybuf, ybf);

  auto run_layer = [&](int l, float* Q, ushort_t* Qbf, const ushort_t* Vbf,
                       int mask_val, bool ffn, bool last) {
    const float* bq_l = bq + (size_t)l * DMODEL;
    const float* bv_l = bv + (size_t)l * DMODEL;
    const float* Wg_l = Wg + (size_t)l * DMODEL * NDYN_C;
    const float* bo_l = bo + (size_t)l * DMODEL;
    const float* g1_l = ln1w + (size_t)l * DMODEL;
    const float* b1_l = ln1b + (size_t)l * DMODEL;
    const ushort_t* WqT_l = WqT + (size_t)l * DMODEL * DMODEL;
    const ushort_t* WvT_l = WvT + (size_t)l * DMODEL * DMODEL;
    const ushort_t* WoT_l = WoT + (size_t)l * DMODEL * DMODEL;

    gemm_qv_router_k<<<dim3(128, 5, 2), 256, 0, stream>>>(
        Qbf, WqT_l, bq_l, qb_bf, WvT_l, Vbf, bv_l, vbT, xbuf, Wg_l, partials);
    if (last)
      router_reduce_k<<<1, 64, 0, stream>>>(partials, out + NA);
    attn_mfma_k<<<512, 256, 0, stream>>>(qb_bf, vbT, partials, ab_bf, mask_val);
    // fused: Q = LN(Q + ab @ Wo + bo), Qbf mirror
    gemm_ln_k<<<512, 256, 0, stream>>>(ab_bf, WoT_l, bo_l, Q, Q, Qbf,
                                       g1_l, b1_l, DMODEL);
    if (ffn) {
      const float* bf1_l = bf1 + (size_t)l * DFF_C;
      const float* bf2_l = bf2 + (size_t)l * DMODEL;
      const float* g2_l = ln2w + (size_t)l * DMODEL;
      const float* b2_l = ln2b + (size_t)l * DMODEL;
      const ushort_t* Wf1T_l = Wf1T + (size_t)l * DMODEL * DFF_C;
      const ushort_t* Wf2T_l = Wf2T + (size_t)l * DFF_C * DMODEL;
      gemm_mfma_k<<<dim3(16, 128), 256, 0, stream>>>(
          2, Qbf, Wf1T_l, bf1_l, hb, NTOK_C, DFF_C, DMODEL);
      // fused: Q(out) = LN(Q + hb @ Wf2 + bf2); last layer writes d_out directly
      gemm_ln_k<<<512, 256, 0, stream>>>(hb, Wf2T_l, bf2_l, Q, last ? out : Q, Qbf,
                                         g2_l, b2_l, DFF_C);
    }
  };

  // blocks_1: y-stream, router input = x (q_embed copy, unchanged during blocks_1)
  run_layer(0, ybuf, ybf, ybf, 1, true, false);
  run_layer(1, ybuf, ybf, ybf, 1, true, false);
  // blocks_2: (self, no FFN) then (cross to y, strict causal, FFN)
  run_layer(2, xbuf, xbf, xbf, 1, false, false);
  run_layer(3, xbuf, xbf, ybf, 0, true, false);
  run_layer(4, xbuf, xbf, xbf, 1, false, false);
  run_layer(5, xbuf, xbf, ybf, 0, true, true);
}

// Round 19
// 499.645 us; speedup vs baseline: 1.0431x; 1.0431x over previous
//
#include <hip/hip_runtime.h>

// RouterKT forward. FINAL (= verified Round 17, 500.5us): bf16-MFMA everywhere,
// swapped-operand flash attention with balanced q-block pairs + counted-vmcnt
// pipeline, fused QV+router launch, fused GEMM+LayerNorm, single prep kernel.

constexpr int DMODEL = 256;
constexpr int SEQ    = 1024;
constexpr int BATCH  = 8;
constexpr int NHEADS = 8;
constexpr int DKDIM  = 32;
constexpr int NDYN_C = 6;
constexpr int NTOK_C = BATCH * SEQ;   // 8192
constexpr int DFF_C  = 1024;

using frag_bf16 = __attribute__((ext_vector_type(8))) short;  // 8 bf16 = 4 VGPR
using f32x4    = __attribute__((ext_vector_type(4))) float;
typedef unsigned short ushort_t;

__device__ __forceinline__ ushort_t f2bf(float f) {
  unsigned u = __float_as_uint(f);
  unsigned r = (u + 0x7fffu + ((u >> 16) & 1u)) >> 16;   // RNE, finite inputs
  return (ushort_t)r;
}

__device__ __forceinline__ unsigned cvt_pk_bf16(float lo, float hi) {
  unsigned r;
  asm("v_cvt_pk_bf16_f32 %0, %1, %2" : "=v"(r) : "v"(lo), "v"(hi));
  return r;
}

#define GLOAD_LDS16(gsrc, ldst)                                             \
  __builtin_amdgcn_global_load_lds(                                         \
      (const __attribute__((address_space(1))) void*)(gsrc),                \
      (__attribute__((address_space(3))) void*)(ldst), 16, 0, 0)

// Explicit drain + order pin + barrier (race-proof prefetch handoff).
#define SYNC_DRAIN()                                                        \
  do {                                                                      \
    asm volatile("s_waitcnt vmcnt(0) lgkmcnt(0)" ::: "memory");             \
    __builtin_amdgcn_sched_barrier(0);                                      \
    __syncthreads();                                                        \
  } while (0)

// Counted-vmcnt barrier (T4): wait until all but the newest N of THIS wave's
// vmem ops retired, then raw s_barrier (no implicit vmcnt(0) drain).
#define CBAR_VM(N)                                                          \
  do {                                                                      \
    asm volatile("s_waitcnt vmcnt(" #N ")" ::: "memory");                   \
    __builtin_amdgcn_sched_barrier(0);                                      \
    __builtin_amdgcn_s_barrier();                                           \
    __builtin_amdgcn_sched_barrier(0);                                      \
  } while (0)

// ---------------- bf16 MFMA GEMM body (2-phase prefetch, explicit drain) ------
// C[m][n] = sum_k A[m][k] * B[n][k] + bias.   A:[M][K] bf16, B:[N][K] bf16.
// Tile: BM=64, BN=64, BK=64, double-buffered. 256 threads = 4 waves (2x2).
// mode: 0 = f32 C, 1 = bf16*QSCALE (q-proj), 2 = bf16+relu, 3 = vbT scatter.
__device__ __forceinline__
void gemm_body(int mode, int bx, int by,
               const ushort_t* __restrict__ A, const ushort_t* __restrict__ B,
               const float* __restrict__ bias, void* __restrict__ Cp,
               int M, int N, int K,
               ushort_t (*sA)[4096], ushort_t (*sB)[4096]) {
  const int tid = threadIdx.x;
  const int wid = tid >> 6, lane = tid & 63;
  const int li = lane & 15, g = lane >> 4;
  const int wr = wid >> 1, wc = wid & 1;
  const int m0 = by * 64, n0 = bx * 64;
  f32x4 acc[2][2] = {};
  const int srow = wid * 8 + (lane >> 3);
  const int schk = (lane & 7) ^ (lane >> 3);
  const ushort_t* gA1 = &A[(size_t)(m0 + srow) * K + schk * 8];
  const ushort_t* gA2 = &A[(size_t)(m0 + 32 + srow) * K + schk * 8];
  const ushort_t* gB1 = &B[(size_t)(n0 + srow) * K + schk * 8];
  const ushort_t* gB2 = &B[(size_t)(n0 + 32 + srow) * K + schk * 8];
  const int nk = K >> 6;

  GLOAD_LDS16(gA1, sA[0] + wid * 512);
  GLOAD_LDS16(gA2, sA[0] + 2048 + wid * 512);
  GLOAD_LDS16(gB1, sB[0] + wid * 512);
  GLOAD_LDS16(gB2, sB[0] + 2048 + wid * 512);
  SYNC_DRAIN();

  auto compute = [&](int cur) {
#pragma unroll
    for (int s = 0; s < 2; ++s) {
      frag_bf16 af[2], bf[2];
#pragma unroll
      for (int m = 0; m < 2; ++m) {
        const int row = wr * 32 + m * 16 + li;
        af[m] = *reinterpret_cast<const frag_bf16*>(
            &sA[cur][row * 64 + ((s * 4 + g) ^ (row & 7)) * 8]);
      }
#pragma unroll
      for (int n = 0; n < 2; ++n) {
        const int row = wc * 32 + n * 16 + li;
        bf[n] = *reinterpret_cast<const frag_bf16*>(
            &sB[cur][row * 64 + ((s * 4 + g) ^ (row & 7)) * 8]);
      }
#pragma unroll
      for (int m = 0; m < 2; ++m)
#pragma unroll
        for (int n = 0; n < 2; ++n)
          acc[m][n] = __builtin_amdgcn_mfma_f32_16x16x32_bf16(af[m], bf[n], acc[m][n], 0, 0, 0);
    }
  };

  for (int kt = 0; kt < nk - 1; ++kt) {
    const int cur = kt & 1;
    const int k1 = (kt + 1) << 6;
    GLOAD_LDS16(gA1 + k1, sA[cur ^ 1] + wid * 512);
    GLOAD_LDS16(gA2 + k1, sA[cur ^ 1] + 2048 + wid * 512);
    GLOAD_LDS16(gB1 + k1, sB[cur ^ 1] + wid * 512);
    GLOAD_LDS16(gB2 + k1, sB[cur ^ 1] + 2048 + wid * 512);
    compute(cur);
    SYNC_DRAIN();
  }
  compute((nk - 1) & 1);

  constexpr float QSCALE = 0.42044820762685725f;  // 32^-0.25; k=q so (qs)(ks)=qk/sqrt(32)
#pragma unroll
  for (int m = 0; m < 2; ++m)
#pragma unroll
    for (int n = 0; n < 2; ++n)
#pragma unroll
      for (int r = 0; r < 4; ++r) {
        const int mg = m0 + wr * 32 + m * 16 + g * 4 + r;
        const int ng = n0 + wc * 32 + n * 16 + li;
        if (mode == 0) {
          ((float*)Cp)[(size_t)mg * N + ng] = acc[m][n][r] + bias[ng];
        } else if (mode == 1) {
          ((ushort_t*)Cp)[(size_t)mg * N + ng] = f2bf((acc[m][n][r] + bias[ng]) * QSCALE);
        } else if (mode == 2) {
          ((ushort_t*)Cp)[(size_t)mg * N + ng] = f2bf(fmaxf(acc[m][n][r] + bias[ng], 0.0f));
        } else {
          ((ushort_t*)Cp)[((size_t)((ng >> 10) * 256 + mg)) * SEQ + (ng & 1023)] =
              f2bf(acc[m][n][r] + bias[mg]);
        }
      }
}

__global__ __launch_bounds__(256)
void gemm_mfma_k(int mode, const ushort_t* __restrict__ A, const ushort_t* __restrict__ B,
                 const float* __restrict__ bias, void* __restrict__ Cp,
                 int M, int N, int K) {
  __shared__ ushort_t sA[2][4096];
  __shared__ ushort_t sB[2][4096];
  gemm_body(mode, blockIdx.x, blockIdx.y, A, B, bias, Cp, M, N, K, sA, sB);
}

// ---------------- fused GEMM (N=256 full width) + bias + residual + LayerNorm --
// BM=16, BN=256, BK=64, 2-phase prefetch. Grid 512 (2 blocks/CU).
__global__ __launch_bounds__(256)
void gemm_ln_k(const ushort_t* __restrict__ A, const ushort_t* __restrict__ B,
               const float* __restrict__ bias,
               const float* __restrict__ Xin, float* __restrict__ Xout,
               ushort_t* __restrict__ Xbf,
               const float* __restrict__ gam, const float* __restrict__ bet,
               int K) {
  __shared__ ushort_t sA[2][1024];     // 16 x 64
  __shared__ ushort_t sB[2][16384];    // 256 x 64
  __shared__ float ws1[4][16];
  __shared__ float ws2[4][16];
  const int tid = threadIdx.x;
  const int wid = tid >> 6, lane = tid & 63;
  const int li = lane & 15, g = lane >> 4;
  const int wc = wid;                  // 0..3: 64-col slab
  const int m0 = blockIdx.x * 16;
  f32x4 acc[4] = {};
  const int arow = (wid & 1) * 8 + (lane >> 3);
  const int achk = (lane & 7) ^ (lane >> 3);          // arow&7 == lane>>3
  const ushort_t* gA = &A[(size_t)(m0 + arow) * K + achk * 8];
  const int srow = tid >> 3;           // 0..31
  const int schk = (tid & 7) ^ (srow & 7);
  const ushort_t* gB = &B[(size_t)srow * K + schk * 8];
  const int nk = K >> 6;

  auto stage = [&](int k0, int buf) {
    if (wid < 2) GLOAD_LDS16(gA + k0, sA[buf] + wid * 512);
#pragma unroll
    for (int i = 0; i < 8; ++i)
      GLOAD_LDS16(gB + (size_t)i * 32 * K + k0, sB[buf] + i * 2048 + wid * 512);
  };

  stage(0, 0);
  SYNC_DRAIN();

  auto compute = [&](int cur) {
#pragma unroll
    for (int s = 0; s < 2; ++s) {
      frag_bf16 af, bf[4];
      af = *reinterpret_cast<const frag_bf16*>(
          &sA[cur][li * 64 + ((s * 4 + g) ^ (li & 7)) * 8]);
#pragma unroll
      for (int n = 0; n < 4; ++n) {
        const int row = wc * 64 + n * 16 + li;
        bf[n] = *reinterpret_cast<const frag_bf16*>(
            &sB[cur][row * 64 + ((s * 4 + g) ^ (row & 7)) * 8]);
      }
#pragma unroll
      for (int n = 0; n < 4; ++n)
        acc[n] = __builtin_amdgcn_mfma_f32_16x16x32_bf16(af, bf[n], acc[n], 0, 0, 0);
    }
  };

  for (int kt = 0; kt < nk - 1; ++kt) {
    const int cur = kt & 1;
    stage((kt + 1) << 6, cur ^ 1);
    compute(cur);
    SYNC_DRAIN();
  }
  compute((nk - 1) & 1);

  // ---- epilogue: bias + residual, row stats (16 rows), LN, dual store ----
  float xv[4][4];
  float s1[4] = {}, s2[4] = {};
#pragma unroll
  for (int n = 0; n < 4; ++n)
#pragma unroll
    for (int r = 0; r < 4; ++r) {
      const int row = g * 4 + r;
      const int ng = wc * 64 + n * 16 + li;
      const float x = acc[n][r] + bias[ng] + Xin[(size_t)(m0 + row) * DMODEL + ng];
      xv[n][r] = x;
      s1[r] += x;
      s2[r] += x * x;
    }
#pragma unroll
  for (int mask = 1; mask <= 8; mask <<= 1)
#pragma unroll
    for (int r = 0; r < 4; ++r) {
      s1[r] += __shfl_xor(s1[r], mask, 64);
      s2[r] += __shfl_xor(s2[r], mask, 64);
    }
  if (li == 0) {
#pragma unroll
    for (int r = 0; r < 4; ++r) {
      ws1[wid][g * 4 + r] = s1[r];
      ws2[wid][g * 4 + r] = s2[r];
    }
  }
  __syncthreads();
#pragma unroll
  for (int r = 0; r < 4; ++r) {
    const int row = g * 4 + r;
    const float S1 = ws1[0][row] + ws1[1][row] + ws1[2][row] + ws1[3][row];
    const float S2 = ws2[0][row] + ws2[1][row] + ws2[2][row] + ws2[3][row];
    const float mean = S1 * (1.0f / DMODEL);
    const float var = fmaxf(S2 * (1.0f / DMODEL) - mean * mean, 0.0f);
    const float rstd = 1.0f / sqrtf(var + 1e-5f);
#pragma unroll
    for (int n = 0; n < 4; ++n) {
      const int ng = wc * 64 + n * 16 + li;
      const float rv = (xv[n][r] - mean) * rstd * gam[ng] + bet[ng];
      Xout[(size_t)(m0 + row) * DMODEL + ng] = rv;
      Xbf[(size_t)(m0 + row) * DMODEL + ng] = f2bf(rv);
    }
  }
}

// ---------------- Router body (verified, 128 rows/block, 256-thread guards) ----
__device__ __forceinline__
void router_body(const float* __restrict__ R, const float* __restrict__ Wg,
                 float* __restrict__ partials, float* sW, float (*red)[128]) {
  const int tid = threadIdx.x;
  for (int t = tid; t < DMODEL * NDYN_C; t += 256) sW[t] = Wg[t];
  __syncthreads();
  if (tid < 128) {
    const int r = blockIdx.x * 128 + tid;
    const int b = r >> 10;
    const int h = (r >> 7) & 7;
    const int s8 = r & 127;
    float lg[NDYN_C] = {};
    for (int t8 = 0; t8 < 8; ++t8) {
      const float* base = &R[((size_t)(b * SEQ + s8 * 8 + t8)) * DMODEL + h * DKDIM];
#pragma unroll
      for (int d = 0; d < DKDIM; ++d) {
        const float x = base[d];
        const float* w = &sW[(t8 * 32 + d) * NDYN_C];
#pragma unroll
        for (int j = 0; j < NDYN_C; ++j) lg[j] = fmaf(x, w[j], lg[j]);
      }
    }
    float mx = lg[0];
#pragma unroll
    for (int j = 1; j < NDYN_C; ++j) mx = fmaxf(mx, lg[j]);
    float e[NDYN_C], sum = 0.0f;
#pragma unroll
    for (int j = 0; j < NDYN_C; ++j) { e[j] = expf(lg[j] - mx); sum += e[j]; }
    float g[NDYN_C];
#pragma unroll
    for (int j = 0; j < NDYN_C; ++j) g[j] = e[j] / sum;
    int j1 = 0;
#pragma unroll
    for (int j = 1; j < NDYN_C; ++j) if (g[j] > g[j1]) j1 = j;
    int j2 = -1;
#pragma unroll
    for (int j = 0; j < NDYN_C; ++j) {
      if (j == j1) continue;
      if (j2 < 0 || g[j] > g[j2]) j2 = j;
    }
#pragma unroll
    for (int j = 0; j < NDYN_C; ++j) {
      const bool sel = (j == j1) || (j == j2);
      red[j][tid] = sel ? g[j] : 0.0f;
      red[6 + j][tid] = sel ? 1.0f : 0.0f;
      red[12 + j][tid] = g[j];
    }
  }
  __syncthreads();
  if (tid < 18) {
    float s = 0.0f;
    for (int i = 0; i < 128; ++i) s += red[tid][i];
    partials[blockIdx.x * 18 + tid] = s;
  }
}

// merged Q-projection (mode 1) + V-projection (mode 3) + router slice.
__global__ __launch_bounds__(256)
void gemm_qv_router_k(const ushort_t* __restrict__ Aq, const ushort_t* __restrict__ Bq,
                      const float* __restrict__ biasq, void* __restrict__ Cq,
                      const ushort_t* __restrict__ Av, const ushort_t* __restrict__ Bv,
                      const float* __restrict__ biasv, void* __restrict__ Cv,
                      const float* __restrict__ R, const float* __restrict__ Wg,
                      float* __restrict__ partials) {
  __shared__ ushort_t sA[2][4096];   // 16 KB
  __shared__ ushort_t sB[2][4096];   // 16 KB
  if (blockIdx.y == 4) {
    if (blockIdx.z == 0 && blockIdx.x < 64) {
      float* sW = (float*)&sA[0][0];                   // 6 KB <= 16 KB
      float (*red)[128] = (float(*)[128])&sB[0][0];    // 9 KB <= 16 KB
      router_body(R, Wg, partials, sW, red);
    }
    return;
  }
  if (blockIdx.z == 0)
    gemm_body(1, blockIdx.y, blockIdx.x, Aq, Bq, biasq, Cq, NTOK_C, DMODEL, DMODEL, sA, sB);
  else
    gemm_body(3, blockIdx.x, blockIdx.y, Av, Bv, biasv, Cv, DMODEL, NTOK_C, DMODEL, sA, sB);
}

// ---------------- weight transpose body ----------------
__device__ __forceinline__
void transpose_body(const float* __restrict__ ip, ushort_t* __restrict__ op, int R, int C,
                    int c0, int r0) {
  __shared__ float t[32][33];
  const int tx = threadIdx.x & 31, ty = threadIdx.x >> 5;   // ty 0..7
#pragma unroll
  for (int i = 0; i < 4; ++i) t[ty + 8 * i][tx] = ip[(size_t)(r0 + ty + 8 * i) * C + c0 + tx];
  __syncthreads();
#pragma unroll
  for (int i = 0; i < 4; ++i)
    op[(size_t)(c0 + ty + 8 * i) * R + r0 + tx] = f2bf(t[tx][ty + 8 * i]);
}

// ---------------- ALL weight prep + activation init in ONE launch --------------
// grid 8320: [0,1152) Wq/Wv/Wo transposes; [1152,2688) Wf1; [2688,4224) Wf2;
// [4224,8320) f32 copy + bf16 mirror of both activation streams.
__global__ __launch_bounds__(256)
void prep_k(const float* __restrict__ Wq, ushort_t* __restrict__ WqT,
            const float* __restrict__ Wv, ushort_t* __restrict__ WvT,
            const float* __restrict__ Wo, ushort_t* __restrict__ WoT,
            const float* __restrict__ Wf1, ushort_t* __restrict__ Wf1T,
            const float* __restrict__ Wf2, ushort_t* __restrict__ Wf2T,
            const float* __restrict__ q_embed, float* __restrict__ xbuf,
            ushort_t* __restrict__ xbf,
            const float* __restrict__ qa_embed, float* __restrict__ ybuf,
            ushort_t* __restrict__ ybf) {
  const int id = blockIdx.x;
  if (id < 1152) {                     // 18 z-slices of 8x8 blocks (256x256 stacks)
    const int z = id >> 6, rem = id & 63;
    const int zi = z / 6, zz = z % 6;
    const float* in = (zi == 0) ? Wq : (zi == 1) ? Wv : Wo;
    ushort_t* outp = (zi == 0) ? WqT : (zi == 1) ? WvT : WoT;
    transpose_body(in + (size_t)zz * DMODEL * DMODEL, outp + (size_t)zz * DMODEL * DMODEL,
                   DMODEL, DMODEL, (rem & 7) * 32, (rem >> 3) * 32);
  } else if (id < 2688) {              // Wf1 [6][256][1024] -> [6][1024][256]
    const int t = id - 1152;
    const int z = t >> 8, rem = t & 255;
    transpose_body(Wf1 + (size_t)z * DMODEL * DFF_C, Wf1T + (size_t)z * DMODEL * DFF_C,
                   DMODEL, DFF_C, (rem & 31) * 32, (rem >> 5) * 32);
  } else if (id < 4224) {              // Wf2 [6][1024][256] -> [6][256][1024]
    const int t = id - 2688;
    const int z = t >> 8, rem = t & 255;
    transpose_body(Wf2 + (size_t)z * DFF_C * DMODEL, Wf2T + (size_t)z * DFF_C * DMODEL,
                   DFF_C, DMODEL, (rem & 7) * 32, (rem >> 3) * 32);
  } else {                             // activation copy+mirror (4096 blocks)
    const int t = id - 4224;
    const int yy = t >> 11, xx = t & 2047;
    const float* src = yy ? qa_embed : q_embed;
    float* dstF = yy ? ybuf : xbuf;
    ushort_t* dstB = yy ? ybf : xbf;
    const int i = xx * 256 + threadIdx.x;       // over float4 elements
    const float4 v = reinterpret_cast<const float4*>(src)[i];
    reinterpret_cast<float4*>(dstF)[i] = v;
    ushort4 bb;
    bb.x = f2bf(v.x); bb.y = f2bf(v.y); bb.z = f2bf(v.z); bb.w = f2bf(v.w);
    reinterpret_cast<ushort4*>(dstB)[i] = bb;
  }
}

// ---------------- MFMA flash attention: balanced q-block pairs (verified) ------
// grid 512: b = gid&7 (XCD-local K/V); slot=gid>>3: h=slot>>3, pair=slot&7.
// Each block runs TWO q-blocks {15-pair, pair}: uniform 17 tile-steps per block.
__global__ __launch_bounds__(256)
void attn_mfma_k(const ushort_t* __restrict__ qb, const ushort_t* __restrict__ vbT,
                 const float* __restrict__ partials, ushort_t* __restrict__ out,
                 int mask_val) {
  __shared__ ushort_t sk[3][2048];   // K tile: [kb 4][g 4][li=key 16][8] frag-linear
  __shared__ ushort_t sv[3][2048];   // V^T tile: [d 32][8 chunks, slot = ch^(d&7)][8]
  __shared__ ushort_t pbuf[4096];    // per-wave P^T frag-linear
  const int gid = blockIdx.x;
  const int b = gid & 7;
  const int slot = gid >> 3;
  const int h = (slot >> 3) & 7;
  const int pair = slot & 7;
  const int tid = threadIdx.x;
  const int wave = tid >> 6, lane = tid & 63;
  const int g = lane >> 4, li = lane & 15;
  ushort_t* pP = &pbuf[wave * 1024];

  const ushort_t* gK = &qb[((size_t)(b * SEQ + wave * 16 + li)) * DMODEL + h * DKDIM + g * 8];
  const ushort_t* gV = &vbT[((size_t)((b * NHEADS + h) * DKDIM) + wave * 8 + (lane >> 3)) * SEQ
                            + ((lane & 7) ^ (lane >> 3)) * 8];

  // rt from partials: 1 for shared heads, mean gate otherwise (same order as reduce).
  float rt = 1.0f;
  if (h >= 2) {
    const int j = h - 2;
    float sr = 0.f;
#pragma unroll
    for (int t = 0; t < 8; ++t) sr += partials[(b * 8 + t) * 18 + j];
    rt = sr * (1.0f / 1024.0f);
  }

  auto issue = [&](int i, int bi) {
    GLOAD_LDS16(gK + (size_t)(i * 64) * DMODEL, sk[bi] + wave * 512);
    GLOAD_LDS16(gV + i * 64, sv[bi] + wave * 512);
  };

  auto process = [&](int qblk) {
    const int q0 = qblk * 64;
    const int qw = q0 + wave * 16;
    const int qrow = qw + li;          // this lane's q row
    const frag_bf16 qf = *reinterpret_cast<const frag_bf16*>(
        &qb[((size_t)(b * SEQ + qrow)) * DMODEL + h * DKDIM + g * 8]);
    float mrun = -INFINITY, lrun = 0.f;
    f32x4 o0 = {0.f, 0.f, 0.f, 0.f}, o1 = {0.f, 0.f, 0.f, 0.f};  // O^T
    const int nt = qblk + 1;

    auto tile_step = [&](int t, int cur) {
      const int kt = t * 64;
      f32x4 s[4];
#pragma unroll
      for (int kb = 0; kb < 4; ++kb) {
        frag_bf16 kf = *reinterpret_cast<const frag_bf16*>(&sk[cur][(kb * 64 + g * 16 + li) * 8]);
        f32x4 z = {0.f, 0.f, 0.f, 0.f};
        s[kb] = __builtin_amdgcn_mfma_f32_16x16x32_bf16(kf, qf, z, 0, 0, 0);
      }
      const bool need_mask = (kt + 63) >= (qw + mask_val);
      if (need_mask) {
#pragma unroll
        for (int kb = 0; kb < 4; ++kb)
#pragma unroll
          for (int r = 0; r < 4; ++r) {
            const int col = kt + kb * 16 + 4 * g + r;
            if (col >= (qrow + mask_val)) s[kb][r] = -1e9f;
          }
      }
      float tm = -INFINITY;
#pragma unroll
      for (int kb = 0; kb < 4; ++kb)
#pragma unroll
        for (int r = 0; r < 4; ++r) tm = fmaxf(tm, s[kb][r]);
      tm = fmaxf(tm, __shfl_xor(tm, 16, 64));
      tm = fmaxf(tm, __shfl_xor(tm, 32, 64));
      const float mnew = fmaxf(mrun, tm);
      const float scl = __expf(mrun - mnew);
      float p[4][4];
      float psum = 0.f;
#pragma unroll
      for (int kb = 0; kb < 4; ++kb)
#pragma unroll
        for (int r = 0; r < 4; ++r) { p[kb][r] = __expf(s[kb][r] - mnew); psum += p[kb][r]; }
      psum += __shfl_xor(psum, 16, 64);
      psum += __shfl_xor(psum, 32, 64);
      lrun = lrun * scl + psum;
      mrun = mnew;
#pragma unroll
      for (int r = 0; r < 4; ++r) { o0[r] *= scl; o1[r] *= scl; }
#pragma unroll
      for (int kb = 0; kb < 4; ++kb)
#pragma unroll
        for (int pr = 0; pr < 2; ++pr) {
          const unsigned pk = cvt_pk_bf16(p[kb][2 * pr], p[kb][2 * pr + 1]);
          const int addr = (((kb >> 1) * 4 + (kb & 1) * 2 + (g >> 1)) * 16 + li) * 8
                           + 4 * (g & 1) + 2 * pr;
          *reinterpret_cast<unsigned*>(&pP[addr]) = pk;
        }
      __threadfence_block();
#pragma unroll
      for (int c = 0; c < 2; ++c) {
        frag_bf16 pf = *reinterpret_cast<const frag_bf16*>(&pP[((c * 4 + g) * 16 + li) * 8]);
        frag_bf16 vf0 = *reinterpret_cast<const frag_bf16*>(
            &sv[cur][li * 64 + ((4 * c + g) ^ (li & 7)) * 8]);
        frag_bf16 vf1 = *reinterpret_cast<const frag_bf16*>(
            &sv[cur][(16 + li) * 64 + ((4 * c + g) ^ (li & 7)) * 8]);
        o0 = __builtin_amdgcn_mfma_f32_16x16x32_bf16(vf0, pf, o0, 0, 0, 0);
        o1 = __builtin_amdgcn_mfma_f32_16x16x32_bf16(vf1, pf, o1, 0, 0, 0);
      }
    };

    // prologue: stage tiles 0 (and 1); wait for tile 0 only.
    issue(0, 0);
    if (nt > 1) {
      issue(1, 1);
      CBAR_VM(2);
    } else {
      CBAR_VM(0);
    }

    int cur = 0;
    for (int t = 0; t < nt; ++t) {
      const bool have2 = (t + 2 < nt);
      if (have2) issue(t + 2, (cur + 2 >= 3) ? cur - 1 : cur + 2);
      tile_step(t, cur);
      if (t + 1 < nt) {
        if (have2) { CBAR_VM(2); } else { CBAR_VM(0); }
      }
      cur = (cur + 1 == 3) ? 0 : cur + 1;
    }

    const float mult = rt / lrun;
    if (!(mask_val == 0 && qrow == 0)) {
      const size_t base = (size_t)(b * SEQ + qrow) * DMODEL + h * DKDIM;
      ushort4 w0, w1;
      w0.x = f2bf(o0[0] * mult); w0.y = f2bf(o0[1] * mult);
      w0.z = f2bf(o0[2] * mult); w0.w = f2bf(o0[3] * mult);
      w1.x = f2bf(o1[0] * mult); w1.y = f2bf(o1[1] * mult);
      w1.z = f2bf(o1[2] * mult); w1.w = f2bf(o1[3] * mult);
      *reinterpret_cast<ushort4*>(&out[base + 4 * g]) = w0;
      *reinterpret_cast<ushort4*>(&out[base + 16 + 4 * g]) = w1;
    }
    // fused row0 patch: out[b,0,h,:] = mean_k(V[k,:]) * rt
    if (mask_val == 0 && qblk == 0 && wave == 0) {
      const int d = lane >> 1, hf = lane & 1;
      const ushort_t* src = &vbT[(((size_t)(b * NHEADS + h)) * DKDIM + d) * SEQ + hf * 512];
      float s = 0.f;
      for (int k = 0; k < 512; k += 8) {
        frag_bf16 v = *reinterpret_cast<const frag_bf16*>(&src[k]);
#pragma unroll
        for (int j = 0; j < 8; ++j)
          s += __uint_as_float(((unsigned)(ushort_t)v[j]) << 16);
      }
      s += __shfl_xor(s, 1, 64);
      if (hf == 0)
        out[(size_t)(b * SEQ) * DMODEL + h * DKDIM + d] = f2bf(s * (1.0f / 1024.0f) * rt);
    }
  };

  process(15 - pair);   // heavy phase: nt = 16-pair (9..16)
  SYNC_DRAIN();         // phase handoff: no in-flight loads / pending LDS reads
  process(pair);        // light phase: nt = pair+1 (1..8); total = 17 per block
}

// ---------------- router finalize: launched ONLY for the last layer (bal) -----
__global__ void router_reduce_k(const float* __restrict__ partials,
                                float* __restrict__ bal_out) {
  if (threadIdx.x == 0) {
    float hs[6], hp[6];
    float hssum = 0.0f, hpsum = 0.0f;
    for (int j = 0; j < 6; ++j) {
      float a = 0.0f, c = 0.0f;
      for (int bi = 0; bi < 64; ++bi) {
        a += partials[bi * 18 + 6 + j];
        c += partials[bi * 18 + 12 + j];
      }
      hs[j] = a;
      hp[j] = c * (1.0f / 8192.0f);
      hssum += hs[j];
      hpsum += hp[j];
    }
    float bal = 0.0f;
    for (int j = 0; j < 6; ++j)
      bal += (hs[j] / (hssum + 1e-5f)) * (hp[j] / (hpsum + 1e-5f));
    *bal_out = bal;
  }
}

// ---------------- driver ----------------
extern "C" void kernel_launch(void* const* d_in, const int* in_sizes, int n_in,
                              void* d_out, int out_size, void* d_ws, size_t ws_size,
                              hipStream_t stream) {
  const float* q_embed  = (const float*)d_in[0];
  const float* qa_embed = (const float*)d_in[1];
  const float* Wq  = (const float*)d_in[2];
  const float* bq  = (const float*)d_in[3];
  const float* Wv  = (const float*)d_in[4];
  const float* bv  = (const float*)d_in[5];
  const float* Wg  = (const float*)d_in[6];
  const float* Wo  = (const float*)d_in[7];
  const float* bo  = (const float*)d_in[8];
  const float* ln1w = (const float*)d_in[9];
  const float* ln1b = (const float*)d_in[10];
  const float* Wf1 = (const float*)d_in[11];
  const float* bf1 = (const float*)d_in[12];
  const float* Wf2 = (const float*)d_in[13];
  const float* bf2 = (const float*)d_in[14];
  const float* ln2w = (const float*)d_in[15];
  const float* ln2b = (const float*)d_in[16];
  float* out = (float*)d_out;

  const size_t NA = (size_t)NTOK_C * DMODEL;  // 2097152
  float* xbuf = (float*)d_ws;
  float* ybuf = xbuf + NA;
  float* ob   = ybuf + NA;
  float* routing8   = ob + NA;
  float* partials   = routing8 + 64;
  float* balscratch = partials + 64 * 18;
  ushort_t* xbf   = (ushort_t*)(balscratch + 16);
  ushort_t* ybf   = xbf + NA;
  ushort_t* qb_bf = ybf + NA;
  ushort_t* vbT   = qb_bf + NA;
  ushort_t* ab_bf = vbT + NA;
  ushort_t* hb    = ab_bf + NA;                       // NTOK * DFF bf16
  ushort_t* WqT   = hb + (size_t)NTOK_C * DFF_C;
  ushort_t* WvT   = WqT + (size_t)6 * DMODEL * DMODEL;
  ushort_t* WoT   = WvT + (size_t)6 * DMODEL * DMODEL;
  ushort_t* Wf1T  = WoT + (size_t)6 * DMODEL * DMODEL;
  ushort_t* Wf2T  = Wf1T + (size_t)6 * DMODEL * DFF_C;

  // all weight prep + activation init in one launch
  prep_k<<<8320, 256, 0, stream>>>(Wq, WqT, Wv, WvT, Wo, WoT, Wf1, Wf1T, Wf2, Wf2T,
                                   q_embed, xbuf, xbf, qa_embed, ybuf, ybf);

  auto run_layer = [&](int l, float* Q, ushort_t* Qbf, const ushort_t* Vbf,
                       int mask_val, bool ffn, bool last) {
    const float* bq_l = bq + (size_t)l * DMODEL;
    const float* bv_l = bv + (size_t)l * DMODEL;
    const float* Wg_l = Wg + (size_t)l * DMODEL * NDYN_C;
    const float* bo_l = bo + (size_t)l * DMODEL;
    const float* g1_l = ln1w + (size_t)l * DMODEL;
    const float* b1_l = ln1b + (size_t)l * DMODEL;
    const ushort_t* WqT_l = WqT + (size_t)l * DMODEL * DMODEL;
    const ushort_t* WvT_l = WvT + (size_t)l * DMODEL * DMODEL;
    const ushort_t* WoT_l = WoT + (size_t)l * DMODEL * DMODEL;

    gemm_qv_router_k<<<dim3(128, 5, 2), 256, 0, stream>>>(
        Qbf, WqT_l, bq_l, qb_bf, WvT_l, Vbf, bv_l, vbT, xbuf, Wg_l, partials);
    if (last)
      router_reduce_k<<<1, 64, 0, stream>>>(partials, out + NA);
    attn_mfma_k<<<512, 256, 0, stream>>>(qb_bf, vbT, partials, ab_bf, mask_val);
    // fused: Q = LN(Q + ab @ Wo + bo), Qbf mirror
    gemm_ln_k<<<512, 256, 0, stream>>>(ab_bf, WoT_l, bo_l, Q, Q, Qbf,
                                       g1_l, b1_l, DMODEL);
    if (ffn) {
      const float* bf1_l = bf1 + (size_t)l * DFF_C;
      const float* bf2_l = bf2 + (size_t)l * DMODEL;
      const float* g2_l = ln2w + (size_t)l * DMODEL;
      const float* b2_l = ln2b + (size_t)l * DMODEL;
      const ushort_t* Wf1T_l = Wf1T + (size_t)l * DMODEL * DFF_C;
      const ushort_t* Wf2T_l = Wf2T + (size_t)l * DFF_C * DMODEL;
      gemm_mfma_k<<<dim3(16, 128), 256, 0, stream>>>(
          2, Qbf, Wf1T_l, bf1_l, hb, NTOK_C, DFF_C, DMODEL);
      // fused: Q(out) = LN(Q + hb @ Wf2 + bf2); last layer writes d_out directly
      gemm_ln_k<<<512, 256, 0, stream>>>(hb, Wf2T_l, bf2_l, Q, last ? out : Q, Qbf,
                                         g2_l, b2_l, DFF_C);
    }
  };

  // blocks_1: y-stream, router input = x (q_embed copy, unchanged during blocks_1)
  run_layer(0, ybuf, ybf, ybf, 1, true, false);
  run_layer(1, ybuf, ybf, ybf, 1, true, false);
  // blocks_2: (self, no FFN) then (cross to y, strict causal, FFN)
  run_layer(2, xbuf, xbf, xbf, 1, false, false);
  run_layer(3, xbuf, xbf, ybf, 0, true, false);
  run_layer(4, xbuf, xbf, xbf, 1, false, false);
  run_layer(5, xbuf, xbf, ybf, 0, true, true);
}